// Round 13
// baseline (361.582 us; speedup 1.0000x reference)
//
#include <hip/hip_runtime.h>
#include <hip/hip_bf16.h>
#include <math.h>

#define N_NODES  8192
#define N_EDGES  49152
#define E_TOT    57344   // edges + self-loops
#define IN_F     128
#define HID      64
#define NH1      64
#define NH2      5
#define OUT_F    32
#define F1       4096    // NH1*HID
#define F2       160     // NH2*OUT_F
#define N_BONDS  64
#define ET       16      // aggx edge-tile
#define NP       4       // head-group partials for fused gemm12
#define HG       16      // heads per group = NH1/NP

typedef short bf16x8 __attribute__((ext_vector_type(8)));
typedef float f32x4  __attribute__((ext_vector_type(4)));

__device__ __forceinline__ float lrelu(float x){ return x > 0.f ? x : 0.2f*x; }

__device__ __forceinline__ unsigned short bf16_rne(float f){
    unsigned u = __float_as_uint(f);
    unsigned r = u + 0x7FFF + ((u >> 16) & 1);
    return (unsigned short)(r >> 16);
}
__device__ __forceinline__ float bf16f(unsigned short h){
    return __uint_as_float((unsigned)h << 16);
}

// barrier that drains LDS ops but leaves global loads (vmcnt) in flight
__device__ __forceinline__ void block_sync_lds(){
    asm volatile("s_waitcnt lgkmcnt(0)" ::: "memory");
    __builtin_amdgcn_s_barrier();
    asm volatile("" ::: "memory");
}

// async global->LDS, 16B per lane; LDS dest is the WAVE-UNIFORM chunk base
// (hardware writes base + lane*16). Global src is per-lane.
__device__ __forceinline__ void gload_lds16(const unsigned short* gp, unsigned short* lp_base){
    __builtin_amdgcn_global_load_lds(
        (const __attribute__((address_space(1))) unsigned int*)(const void*)gp,
        (__attribute__((address_space(3))) unsigned int*)(void*)lp_base,
        16, 0, 0);
}

// ---- fused: CSR count+scan (block 0) | W1 pack | W2 pack | att vectors ------
// block 0: LDS histogram of dst degrees + in-block prefix scan -> row_start,
//          cursor; zero gemm12 reduction counters.
// blocks [1,129): W1 -> split-bf16 frag order [hg][ks][ct][lane][8]
// blocks [129,289): W2 -> split-bf16 frag order [kc][ni][lane][8]
// blocks [289,321): vv column-major [k][j]
__global__ __launch_bounds__(512) void k_prepscan(const int* __restrict__ ei,
        const float* __restrict__ W1, const float* __restrict__ W2,
        const float* __restrict__ a_s, const float* __restrict__ a_d,
        unsigned short* __restrict__ w1fh, unsigned short* __restrict__ w1fl,
        unsigned short* __restrict__ w2fh, unsigned short* __restrict__ w2fl,
        float* __restrict__ vv,
        int* __restrict__ row_start, int* __restrict__ cursor,
        int* __restrict__ rctr){
    __shared__ int cnt[N_NODES];   // 32 KB (block 0 only uses it)
    __shared__ int wsum8[8];
    int b = blockIdx.x, t = threadIdx.x;
    if (b == 0){
        for (int i = t; i < N_NODES; i += 512) cnt[i] = 0;
        __syncthreads();
        for (int i = t; i < N_EDGES; i += 512) atomicAdd(&cnt[ei[N_EDGES + i]], 1);
        __syncthreads();
        int v[16]; int sum = 0;
        #pragma unroll
        for (int k=0;k<16;k++){ v[k] = cnt[t*16+k] + 1; sum += v[k]; }
        int sc = sum;
        #pragma unroll
        for (int off=1; off<64; off<<=1){
            int up = __shfl_up(sc, off);
            if ((t & 63) >= off) sc += up;
        }
        int wid = t >> 6;
        if ((t & 63) == 63) wsum8[wid] = sc;
        __syncthreads();
        if (t < 8){
            int ws = wsum8[t];
            #pragma unroll
            for (int off=1; off<8; off<<=1){
                int up = __shfl_up(ws, off, 8);
                if (t >= off) ws += up;
            }
            wsum8[t] = ws;             // inclusive wave totals
        }
        __syncthreads();
        int wbase = (wid == 0) ? 0 : wsum8[wid-1];
        int run = wbase + sc - sum;    // exclusive prefix
        #pragma unroll
        for (int k=0;k<16;k++){ row_start[t*16+k] = run; cursor[t*16+k] = run; run += v[k]; }
        if (t == 511) row_start[N_NODES] = wsum8[7];
        if (t < 128) rctr[t] = 0;
    } else if (b < 129){
        int g = (b-1)*512 + t;                    // 65536 groups
        int lane = g & 63, ct = (g >> 6) & 3, ks = (g >> 8) & 3, hg = g >> 10;
        int col = hg*64 + ct*16 + (lane & 15);
        int k = ks*32 + (lane >> 4)*8;
        const float* src = W1 + (size_t)col*IN_F + k;
        bf16x8 hv, lv;
        #pragma unroll
        for (int j=0;j<8;j++){
            float f = src[j];
            unsigned short hb = bf16_rne(f);
            hv[j] = (short)hb;
            lv[j] = (short)bf16_rne(f - bf16f(hb));
        }
        *(bf16x8*)(w1fh + (size_t)g*8) = hv;
        *(bf16x8*)(w1fl + (size_t)g*8) = lv;
    } else if (b < 289){
        int g = (b-129)*512 + t;                  // 81920 groups
        int lane = g & 63, ni = (g >> 6) % 10, kc = g / 640;
        int n = ni*16 + (lane & 15);
        int k = kc*32 + (lane >> 4)*8;
        const float* src = W2 + (size_t)n*F1 + k;
        bf16x8 hv, lv;
        #pragma unroll
        for (int j=0;j<8;j++){
            float f = src[j];
            unsigned short hb = bf16_rne(f);
            hv[j] = (short)hb;
            lv[j] = (short)bf16_rne(f - bf16f(hb));
        }
        *(bf16x8*)(w2fh + (size_t)g*8) = hv;
        *(bf16x8*)(w2fl + (size_t)g*8) = lv;
    } else {
        int idx = (b-289)*512 + t;                // 16384 = 128 j x 128 k
        int j = idx >> 7, k = idx & 127;
        int h = j & 63;
        const float* ap = (j < 64) ? a_s : a_d;
        float s = 0.f;
        for (int c = 0; c < HID; c++)
            s += ap[h*HID + c] * W1[(size_t)(h*HID + c)*IN_F + k];
        vv[k*128 + j] = s;
    }
}

// ---- fused: CSR fill | alpha1 dots (grid-range split) -----------------------
__global__ __launch_bounds__(256) void k_fillalpha(const int* __restrict__ ei,
        int* cursor, int* __restrict__ csr_src,
        const float* __restrict__ x, const float* __restrict__ vv,
        float* __restrict__ as1, float* __restrict__ ad1){
    int b = blockIdx.x, t = threadIdx.x;
    if (b < 224){
        int i = b*256 + t;
        if (i >= E_TOT) return;
        int s, d;
        if (i < N_EDGES){ s = ei[i]; d = ei[N_EDGES + i]; }
        else { s = i - N_EDGES; d = s; }
        int pos = atomicAdd(&cursor[d], 1);
        csr_src[pos] = s;
    } else {
        __shared__ float xs[8][IN_F];   // 4 KB
        int bb = b - 224;               // 0..1023
        int nb = bb*8;
        {
            int r = t >> 5, c4 = t & 31;
            *(float4*)&xs[r][c4*4] = *(const float4*)(x + (size_t)(nb+r)*IN_F + c4*4);
        }
        __syncthreads();
        int half = t >> 7, tl = t & 127;
        int n0 = nb + half*4;
        float a0=0.f, a1=0.f, a2=0.f, a3=0.f;
        #pragma unroll 4
        for (int k=0;k<IN_F;k++){
            float v = vv[k*128 + tl];
            a0 += xs[half*4+0][k]*v; a1 += xs[half*4+1][k]*v;
            a2 += xs[half*4+2][k]*v; a3 += xs[half*4+3][k]*v;
        }
        int hd = tl & 63;
        float* outp = (tl < 64) ? as1 : ad1;
        outp[(n0+0)*NH1 + hd] = a0;
        outp[(n0+1)*NH1 + hd] = a1;
        outp[(n0+2)*NH1 + hd] = a2;
        outp[(n0+3)*NH1 + hd] = a3;
    }
}

// ------- x-space aggregation, ALL 64 heads, denom fused, single dispatch -----
__global__ __launch_bounds__(256) void k_aggx64(const float* __restrict__ x,
        const float* __restrict__ as1, const float* __restrict__ ad1,
        const int* __restrict__ row_start, const int* __restrict__ csr_src,
        unsigned short* __restrict__ txhi){
    int n = blockIdx.x, t = threadIdx.x;
    __shared__ float ad_s[NH1];
    __shared__ float wt[ET][NH1];   // 4 KB
    __shared__ int   st[ET];
    __shared__ float xs[ET][IN_F];  // 8 KB
    int e0 = row_start[n], e1 = row_start[n+1];
    if (t < NH1) ad_s[t] = ad1[n*NH1 + t];
    int hq = t >> 4, f0 = (t & 15)*8;
    float acc[4][8] = {};
    float D[4] = {0.f, 0.f, 0.f, 0.f};
    for (int eb = e0; eb < e1; eb += ET){
        int ne = min(ET, e1 - eb);
        if (t < ne) st[t] = csr_src[eb + t];
        __syncthreads();
        for (int idx = t; idx < ne*32; idx += 256){
            int e = idx >> 5, f4 = idx & 31;
            *(float4*)&xs[e][f4*4] = *(const float4*)(x + (size_t)st[e]*IN_F + f4*4);
        }
        for (int idx = t; idx < ne*NH1; idx += 256){
            int e = idx >> 6, hh = idx & 63;
            wt[e][hh] = __expf(lrelu(as1[st[e]*NH1 + hh] + ad_s[hh]));
        }
        __syncthreads();
        for (int e = 0; e < ne; e++){
            float4 v0 = *(const float4*)&xs[e][f0];
            float4 v1 = *(const float4*)&xs[e][f0+4];
            float xv[8] = {v0.x,v0.y,v0.z,v0.w,v1.x,v1.y,v1.z,v1.w};
            #pragma unroll
            for (int c=0;c<4;c++){
                float w = wt[e][hq*4 + c];
                D[c] += w;
                #pragma unroll
                for (int j=0;j<8;j++) acc[c][j] += w*xv[j];
            }
        }
        __syncthreads();
    }
    #pragma unroll
    for (int c=0;c<4;c++){
        float dinv = 1.f / D[c];
        bf16x8 hv;
        #pragma unroll
        for (int j=0;j<8;j++) hv[j] = (short)bf16_rne(acc[c][j] * dinv);
        size_t o = ((size_t)(hq*4 + c)*N_NODES + n)*IN_F + f0;
        *(bf16x8*)(txhi + o) = hv;
    }
}

// ------- FUSED layer-1 projection + ELU + layer-2 projection -----------------
// PROVEN R6/R11 K-loop (~59.5 us) + last-block partial reduction in the tail
// (replaces k_redalpha). LDS exactly 80 KB (2 blocks/CU). After the epilogue:
// threadfence -> extra barrier (retires GEMM2 LDS reads) -> tid0 atomicAdd on
// rctr[m], result in dead X1s word -> 4th block acquires, reduces 4 partials
// for its 64 rows into h2 + LDS scratch (dead Als/W1sh region), computes
// as2/ad2. Same reduction order as k_redalpha -> bit-identical.
__global__ __launch_bounds__(512, 4) void k_gemm12(
        const unsigned short* __restrict__ txhi,
        const unsigned short* __restrict__ w1fh, const unsigned short* __restrict__ w1fl,
        const unsigned short* __restrict__ w2fh, const unsigned short* __restrict__ w2fl,
        const float* __restrict__ b1,
        float* __restrict__ P,
        const float* __restrict__ att_s2, const float* __restrict__ att_d2,
        float* __restrict__ h2, float* __restrict__ as2, float* __restrict__ ad2,
        int* __restrict__ rctr){
    __shared__ __attribute__((aligned(16))) char smem_[81920];
    unsigned short* Als  = (unsigned short*)smem_;            // 16 KB (64x128 A, swizzled)
    unsigned short* W1sh = (unsigned short*)(smem_ + 16384);  // 16 KB W1 hi frags
    unsigned short* W2s  = (unsigned short*)(smem_ + 32768);  // 40 KB W2 hi+lo frags
    unsigned short* X1s  = (unsigned short*)(smem_ + 73728);  //  8 KB X1 (swizzled)

    const int tid  = threadIdx.x;
    const int wave = tid >> 6, lane = tid & 63;
    const int wr = wave & 1, wc = wave >> 1;
    const int q = lane >> 4, l16 = lane & 15;
    const int row0 = blockIdx.x * 64;
    const int g = blockIdx.y;
    const int h0 = g * HG;
    const int nbase = (wc < 2) ? wc*3 : 6 + (wc-2)*2;   // GEMM2 n-tile base

    // ---- prologue: stage A(h0) + W1hi(h0) (4 issues/wave) ----
    {
        const unsigned short* Ab = txhi + ((size_t)h0*N_NODES + row0)*IN_F;
        const unsigned short* W1b = w1fh + (size_t)h0*8192;
        #pragma unroll
        for (int j=0;j<2;j++){
            int idx = j*8 + wave;
            int eo = idx*512 + lane*8;
            int row = eo >> 7;
            int se = (eo & ~127) | ((eo & 127) ^ ((row & 7) << 3));
            gload_lds16(Ab + se, &Als[idx*512]);
        }
        #pragma unroll
        for (int j=0;j<2;j++){
            int idx = j*8 + wave;
            gload_lds16(W1b + idx*512 + lane*8, &W1sh[idx*512]);
        }
    }

    f32x4 acc2[2][3] = {};
    bf16x8 wlo[4];

    #pragma unroll 1
    for (int hh = 0; hh < HG; hh++){
        const int h = h0 + hh;
        block_sync_lds();                       // B_top: prev GEMM2 done with W2s/X1s
        // ---- W1 lo-plane fragments -> regs FIRST (oldest after staged A/W1hi) ----
        {
            const unsigned short* W1lb = w1fl + (size_t)h*8192;
            #pragma unroll
            for (int ks=0;ks<4;ks++)
                wlo[ks] = *(const bf16x8*)(W1lb + (size_t)(ks*4 + wc)*512 + lane*8);
        }
        asm volatile("" ::: "memory");          // pin: wlo issued before W2 staging
        // ---- stage W2 hi+lo for h (5 issues/wave) ----
        {
            const unsigned short* W2bh = w2fh + (size_t)h*10240;
            const unsigned short* W2bl = w2fl + (size_t)h*10240;
            #pragma unroll
            for (int j=0;j<5;j++){
                int idx = j*8 + wave;             // 0..39 (idx<20 -> hi plane)
                const unsigned short* src = (idx < 20) ? (W2bh + idx*512 + lane*8)
                                                       : (W2bl + (idx-20)*512 + lane*8);
                gload_lds16(src, &W2s[idx*512]);
            }
        }
        // outstanding: A/W1hi(4, oldest) + wlo(4) + W2(5) = 13 -> drain only A/W1hi
        asm volatile("s_waitcnt vmcnt(9)" ::: "memory");
        __builtin_amdgcn_s_barrier();           // B_mid: A/W1hi staging visible
        // ---- GEMM1: X1 = A[h] @ W1[h]^T (hi LDS, lo regs); B reused x2 ----
        f32x4 c1[2] = {};
        __builtin_amdgcn_s_setprio(1);
        #pragma unroll
        for (int ks=0;ks<4;ks++){
            bf16x8 bh = *(const bf16x8*)&W1sh[(ks*4 + wc)*512 + lane*8];
            #pragma unroll
            for (int mi=0;mi<2;mi++){
                int arow = wr*32 + mi*16 + l16;
                int sidx = (arow*128 + ks*32 + q*8) ^ ((arow & 7) << 3);
                bf16x8 af = *(const bf16x8*)&Als[sidx];
                c1[mi] = __builtin_amdgcn_mfma_f32_16x16x32_bf16(af, bh, c1[mi], 0,0,0);
                c1[mi] = __builtin_amdgcn_mfma_f32_16x16x32_bf16(af, wlo[ks], c1[mi], 0,0,0);
            }
        }
        __builtin_amdgcn_s_setprio(0);
        // ---- bias + fast ELU -> X1s (swizzled bf16) ----
        {
            int col = wc*16 + l16;
            float b = b1[h*64 + col];
            #pragma unroll
            for (int mi=0;mi<2;mi++){
                #pragma unroll
                for (int i=0;i<4;i++){
                    float v = c1[mi][i] + b;
                    float o = v > 0.f ? v : (__expf(v) - 1.f);
                    int row = wr*32 + mi*16 + q*4 + i;
                    int sidx = (row*64 + col) ^ ((row & 7) << 3);
                    X1s[sidx] = bf16_rne(o);
                }
            }
        }
        // drain W2 (only it remains in flight) under the GEMM1+ELU shadow
        asm volatile("s_waitcnt vmcnt(0) lgkmcnt(0)" ::: "memory");
        __builtin_amdgcn_s_barrier();           // B_vis: X1 + W2 staging visible
        // ---- stage A(h+1) + W1hi(h+1); loads fly across GEMM2 + next B_top ----
        if (hh + 1 < HG){
            const unsigned short* Ab = txhi + ((size_t)(h+1)*N_NODES + row0)*IN_F;
            const unsigned short* W1b = w1fh + (size_t)(h+1)*8192;
            #pragma unroll
            for (int j=0;j<2;j++){
                int idx = j*8 + wave;
                int eo = idx*512 + lane*8;
                int row = eo >> 7;
                int se = (eo & ~127) | ((eo & 127) ^ ((row & 7) << 3));
                gload_lds16(Ab + se, &Als[idx*512]);
            }
            #pragma unroll
            for (int j=0;j<2;j++){
                int idx = j*8 + wave;
                gload_lds16(W1b + idx*512 + lane*8, &W1sh[idx*512]);
            }
        }
        // ---- GEMM2: acc2 += X1 @ W2[h-slice]^T (all LDS); B reused x2 over mi ----
        __builtin_amdgcn_s_setprio(1);
        #pragma unroll
        for (int ks=0;ks<2;ks++){
            bf16x8 a2[2];
            #pragma unroll
            for (int mi=0;mi<2;mi++){
                int row = wr*32 + mi*16 + l16;
                int sidx = (row*64 + ks*32 + q*8) ^ ((row & 7) << 3);
                a2[mi] = *(const bf16x8*)&X1s[sidx];
            }
            if (wc < 2){
                #pragma unroll
                for (int ni=0;ni<3;ni++){
                    int f = (ks*10 + nbase + ni)*512 + lane*8;
                    bf16x8 bh = *(const bf16x8*)&W2s[f];
                    bf16x8 bl = *(const bf16x8*)&W2s[10240 + f];
                    #pragma unroll
                    for (int mi=0;mi<2;mi++){
                        acc2[mi][ni] = __builtin_amdgcn_mfma_f32_16x16x32_bf16(a2[mi], bh, acc2[mi][ni], 0,0,0);
                        acc2[mi][ni] = __builtin_amdgcn_mfma_f32_16x16x32_bf16(a2[mi], bl, acc2[mi][ni], 0,0,0);
                    }
                }
            } else {
                #pragma unroll
                for (int ni=0;ni<2;ni++){
                    int f = (ks*10 + nbase + ni)*512 + lane*8;
                    bf16x8 bh = *(const bf16x8*)&W2s[f];
                    bf16x8 bl = *(const bf16x8*)&W2s[10240 + f];
                    #pragma unroll
                    for (int mi=0;mi<2;mi++){
                        acc2[mi][ni] = __builtin_amdgcn_mfma_f32_16x16x32_bf16(a2[mi], bh, acc2[mi][ni], 0,0,0);
                        acc2[mi][ni] = __builtin_amdgcn_mfma_f32_16x16x32_bf16(a2[mi], bl, acc2[mi][ni], 0,0,0);
                    }
                }
            }
        }
        __builtin_amdgcn_s_setprio(0);
    }

    // ---- epilogue: head-group partial store ----
    float* outp = P + ((size_t)g*N_NODES + row0)*F2;
    #pragma unroll
    for (int mi=0;mi<2;mi++)
        #pragma unroll
        for (int ni=0;ni<3;ni++){
            if (wc >= 2 && ni >= 2) continue;    // wave-uniform; indices static
            #pragma unroll
            for (int i=0;i<4;i++){
                int rr = wr*32 + mi*16 + q*4 + i;
                int cc = (nbase + ni)*16 + l16;
                outp[(size_t)rr*F2 + cc] = acc2[mi][ni][i];
            }
        }

    // ---- last-block reduction: 4 partials -> h2 + as2/ad2 for these rows ----
    __threadfence();                       // release: partial stores visible
    __syncthreads();                       // all GEMM2/epilogue LDS reads retired
    volatile int* sdp = (volatile int*)(smem_ + 73728);   // dead X1s word
    if (tid == 0) *sdp = atomicAdd(&rctr[blockIdx.x], 1);
    __syncthreads();
    int done = *sdp;
    if (done == NP-1){
        __threadfence();                   // acquire: see other blocks' partials
        const int NV4 = N_NODES*F2/4;
        const float4* P4 = (const float4*)P;
        float4* h24 = (float4*)h2;
        float* hsf = (float*)smem_;        // [64][164] scratch = 41984 B (dead region)
        #pragma unroll
        for (int v=0; v<5; v++){
            int li = v*512 + tid;          // 0..2559 within 64x160 slab
            int i = row0*40 + li;
            float4 a = P4[i];
            #pragma unroll
            for (int g2=1; g2<NP; g2++){
                float4 b = P4[(size_t)g2*NV4 + i];
                a.x+=b.x; a.y+=b.y; a.z+=b.z; a.w+=b.w;
            }
            h24[i] = a;
            int n = li/40, c4 = li%40;
            *(float4*)&hsf[n*164 + c4*4] = a;
        }
        __syncthreads();
        if (tid < 320){
            int n = tid/5, hh = tid%5;
            const float* hp = &hsf[n*164 + hh*32];
            const float* ap = att_s2 + hh*32;
            const float* dp = att_d2 + hh*32;
            float s=0.f, d=0.f;
            #pragma unroll
            for (int c=0;c<32;c++){ float hv=hp[c]; s += hv*ap[c]; d += hv*dp[c]; }
            as2[(row0+n)*NH2 + hh] = s;
            ad2[(row0+n)*NH2 + hh] = d;
        }
    }
}

// ------- layer-2 softmax + aggregation (SINGLE PASS) + head-mean + b2 --------
__global__ __launch_bounds__(192) void k_agg2(const float* __restrict__ h2,
        const float* __restrict__ as2, const float* __restrict__ ad2,
        const int* __restrict__ row_start, const int* __restrict__ csr_src,
        const float* __restrict__ b2, float* __restrict__ x2){
    int n = blockIdx.x, t = threadIdx.x;
    __shared__ float ad_s[NH2], sacc[F2];
    int e0 = row_start[n], e1 = row_start[n+1];
    if (t < NH2) ad_s[t] = ad2[n*NH2 + t];
    __syncthreads();
    if (t < F2){
        int h = t >> 5;
        float adh = ad_s[h];
        float acc = 0.f, D = 0.f;
        for (int e=e0;e<e1;e++){
            int s = csr_src[e];
            float w = __expf(lrelu(as2[s*NH2 + h] + adh));
            acc += w * h2[(size_t)s*F2 + t];
            D += w;
        }
        sacc[t] = acc / D;
    }
    __syncthreads();
    if (t < OUT_F){
        float v = (sacc[t] + sacc[t+32] + sacc[t+64] + sacc[t+96] + sacc[t+128]) * 0.2f + b2[t];
        x2[n*OUT_F + t] = v;
    }
}

// ---------------- bond scores + softmax over 64 bonds ----------------
__global__ __launch_bounds__(64) void k_bond(const float* __restrict__ x2,
        const int* __restrict__ lefts, const int* __restrict__ rights,
        float* __restrict__ out){
    int b = threadIdx.x;
    int L = lefts[b], R = rights[b];
    float s = 0.f;
    #pragma unroll
    for (int c=0;c<OUT_F;c+=4){
        float4 l4 = *(const float4*)(x2 + (size_t)L*OUT_F + c);
        float4 r4 = *(const float4*)(x2 + (size_t)R*OUT_F + c);
        s += l4.x+l4.y+l4.z+l4.w + r4.x+r4.y+r4.z+r4.w;
    }
    float m = s;
    #pragma unroll
    for (int off=1; off<64; off<<=1) m = fmaxf(m, __shfl_xor(m, off));
    float e = expf(s - m);
    float sum = e;
    #pragma unroll
    for (int off=1; off<64; off<<=1) sum += __shfl_xor(sum, off);
    out[b] = e / sum;
}

extern "C" void kernel_launch(void* const* d_in, const int* in_sizes, int n_in,
                              void* d_out, int out_size, void* d_ws, size_t ws_size,
                              hipStream_t stream){
    const float* x      = (const float*)d_in[0];
    const int*   ei     = (const int*)  d_in[1];
    const int*   lefts  = (const int*)  d_in[2];
    const int*   rights = (const int*)  d_in[3];
    const float* W1     = (const float*)d_in[4];
    const float* att_s1 = (const float*)d_in[5];
    const float* att_d1 = (const float*)d_in[6];
    const float* b1     = (const float*)d_in[7];
    const float* W2     = (const float*)d_in[8];
    const float* att_s2 = (const float*)d_in[9];
    const float* att_d2 = (const float*)d_in[10];
    const float* b2     = (const float*)d_in[11];
    float* out = (float*)d_out;

    // fixed layout (txhi 134 MB dominates)
    char* ws = (char*)d_ws;
    size_t off = 0;
    auto alloc = [&](size_t bytes) -> void* {
        void* p = ws + off;
        off += (bytes + 255) & ~(size_t)255;
        return p;
    };
    unsigned short* txhi = (unsigned short*)alloc((size_t)NH1*N_NODES*IN_F*2); // 134 MB
    float* part   = (float*)alloc((size_t)NP*N_NODES*F2*4);                    // 21 MB
    float* h2     = (float*)alloc((size_t)N_NODES*F2*4);
    float* as1    = (float*)alloc((size_t)N_NODES*NH1*4);
    float* ad1    = (float*)alloc((size_t)N_NODES*NH1*4);
    float* as2    = (float*)alloc((size_t)N_NODES*NH2*4);
    float* ad2    = (float*)alloc((size_t)N_NODES*NH2*4);
    float* x2     = (float*)alloc((size_t)N_NODES*OUT_F*4);
    float* vv     = (float*)alloc((size_t)IN_F*128*4);   // [k][128] s|d columns
    unsigned short* w1fh = (unsigned short*)alloc((size_t)F1*IN_F*2);
    unsigned short* w1fl = (unsigned short*)alloc((size_t)F1*IN_F*2);
    unsigned short* w2fh = (unsigned short*)alloc((size_t)128*10*512*2);
    unsigned short* w2fl = (unsigned short*)alloc((size_t)128*10*512*2);
    int* row_start = (int*)alloc((size_t)(N_NODES+1)*4);
    int* cursor    = (int*)alloc((size_t)N_NODES*4);
    int* csr_src   = (int*)alloc((size_t)E_TOT*4);
    int* rctr      = (int*)alloc((size_t)128*4);

    // CSR count+scan (block 0) ∥ weight packs ∥ attention vectors — 1 dispatch
    k_prepscan<<<321, 512, 0, stream>>>(ei, W1, W2, att_s1, att_d1,
                                        w1fh, w1fl, w2fh, w2fl, vv,
                                        row_start, cursor, rctr);

    // CSR fill ∥ alpha1 dots (one dispatch)
    k_fillalpha<<<1248, 256, 0, stream>>>(ei, cursor, csr_src, x, vv, as1, ad1);

    // layer 1: single-pass aggregation (all heads)
    k_aggx64<<<N_NODES, 256, 0, stream>>>(x, as1, ad1, row_start, csr_src, txhi);

    // FUSED proj1 + ELU + proj2 + last-block partial reduction (h2, as2, ad2)
    k_gemm12<<<dim3(128, NP), 512, 0, stream>>>(txhi, w1fh, w1fl, w2fh, w2fl, b1,
                                                part, att_s2, att_d2, h2, as2, ad2, rctr);

    // layer-2 aggregation: single-pass softmax (fused denominator)
    k_agg2<<<N_NODES, 192, 0, stream>>>(h2, as2, ad2, row_start, csr_src, b2, x2);

    k_bond<<<1, 64, 0, stream>>>(x2, lefts, rights, out);
}

// Round 15
// 209.564 us; speedup vs baseline: 1.7254x; 1.7254x over previous
//
#include <hip/hip_runtime.h>
#include <hip/hip_bf16.h>
#include <math.h>

#define N_NODES  8192
#define N_EDGES  49152
#define E_TOT    57344   // edges + self-loops
#define IN_F     128
#define HID      64
#define NH1      64
#define NH2      5
#define OUT_F    32
#define F1       4096    // NH1*HID
#define F2       160     // NH2*OUT_F
#define N_BONDS  64
#define ET       16      // aggx edge-tile
#define NP       4       // head-group partials for fused gemm12
#define HG       16      // heads per group = NH1/NP

typedef short bf16x8 __attribute__((ext_vector_type(8)));
typedef float f32x4  __attribute__((ext_vector_type(4)));

__device__ __forceinline__ float lrelu(float x){ return x > 0.f ? x : 0.2f*x; }

__device__ __forceinline__ unsigned short bf16_rne(float f){
    unsigned u = __float_as_uint(f);
    unsigned r = u + 0x7FFF + ((u >> 16) & 1);
    return (unsigned short)(r >> 16);
}
__device__ __forceinline__ float bf16f(unsigned short h){
    return __uint_as_float((unsigned)h << 16);
}

// barrier that drains LDS ops but leaves global loads (vmcnt) in flight
__device__ __forceinline__ void block_sync_lds(){
    asm volatile("s_waitcnt lgkmcnt(0)" ::: "memory");
    __builtin_amdgcn_s_barrier();
    asm volatile("" ::: "memory");
}

// async global->LDS, 16B per lane; LDS dest is the WAVE-UNIFORM chunk base
// (hardware writes base + lane*16). Global src is per-lane.
__device__ __forceinline__ void gload_lds16(const unsigned short* gp, unsigned short* lp_base){
    __builtin_amdgcn_global_load_lds(
        (const __attribute__((address_space(1))) unsigned int*)(const void*)gp,
        (__attribute__((address_space(3))) unsigned int*)(void*)lp_base,
        16, 0, 0);
}

// ---- fused: edge-count | W1 pack | W2 pack | attention vectors --------------
// blocks [0,192): count in-degrees (atomics into zeroed counts)
// blocks [192,448): W1 -> split-bf16 frag order [hg][ks][ct][lane][8]
// blocks [448,768): W2 -> split-bf16 frag order [kc][ni][lane][8]
// blocks [768,832): vv column-major [k][j]
__global__ __launch_bounds__(256) void k_countprep(const int* __restrict__ ei,
        int* counts,
        const float* __restrict__ W1, const float* __restrict__ W2,
        const float* __restrict__ a_s, const float* __restrict__ a_d,
        unsigned short* __restrict__ w1fh, unsigned short* __restrict__ w1fl,
        unsigned short* __restrict__ w2fh, unsigned short* __restrict__ w2fl,
        float* __restrict__ vv){
    int b = blockIdx.x, t = threadIdx.x;
    if (b < 192){
        int i = b*256 + t;
        if (i < N_EDGES) atomicAdd(&counts[ei[N_EDGES + i]], 1);
    } else if (b < 448){
        int g = (b-192)*256 + t;                  // 65536 groups
        int lane = g & 63, ct = (g >> 6) & 3, ks = (g >> 8) & 3, hg = g >> 10;
        int col = hg*64 + ct*16 + (lane & 15);
        int k = ks*32 + (lane >> 4)*8;
        const float* src = W1 + (size_t)col*IN_F + k;
        bf16x8 hv, lv;
        #pragma unroll
        for (int j=0;j<8;j++){
            float f = src[j];
            unsigned short hb = bf16_rne(f);
            hv[j] = (short)hb;
            lv[j] = (short)bf16_rne(f - bf16f(hb));
        }
        *(bf16x8*)(w1fh + (size_t)g*8) = hv;
        *(bf16x8*)(w1fl + (size_t)g*8) = lv;
    } else if (b < 768){
        int g = (b-448)*256 + t;                  // 81920 groups
        int lane = g & 63, ni = (g >> 6) % 10, kc = g / 640;
        int n = ni*16 + (lane & 15);
        int k = kc*32 + (lane >> 4)*8;
        const float* src = W2 + (size_t)n*F1 + k;
        bf16x8 hv, lv;
        #pragma unroll
        for (int j=0;j<8;j++){
            float f = src[j];
            unsigned short hb = bf16_rne(f);
            hv[j] = (short)hb;
            lv[j] = (short)bf16_rne(f - bf16f(hb));
        }
        *(bf16x8*)(w2fh + (size_t)g*8) = hv;
        *(bf16x8*)(w2fl + (size_t)g*8) = lv;
    } else {
        int idx = (b-768)*256 + t;                // 16384 = 128 j x 128 k
        int j = idx >> 7, k = idx & 127;
        int h = j & 63;
        const float* ap = (j < 64) ? a_s : a_d;
        float s = 0.f;
        for (int c = 0; c < HID; c++)
            s += ap[h*HID + c] * W1[(size_t)(h*HID + c)*IN_F + k];
        vv[k*128 + j] = s;
    }
}

// counts hold in-degree WITHOUT self-loop (zeroed via memset); scan adds +1.
// Wave-level shfl scan: 2 barriers (bit-exact integer adds).
__global__ __launch_bounds__(1024) void k_scan(const int* __restrict__ counts,
                                               int* __restrict__ row_start,
                                               int* __restrict__ cursor){
    __shared__ int wsum[16];
    int t = threadIdx.x;
    int v[8]; int sum = 0;
    #pragma unroll
    for (int i=0;i<8;i++){ v[i] = counts[t*8+i] + 1; sum += v[i]; }
    int sc = sum;
    #pragma unroll
    for (int off=1; off<64; off<<=1){
        int up = __shfl_up(sc, off);
        if ((t & 63) >= off) sc += up;
    }
    int wid = t >> 6;
    if ((t & 63) == 63) wsum[wid] = sc;
    __syncthreads();
    if (t < 16){
        int ws = wsum[t];
        #pragma unroll
        for (int off=1; off<16; off<<=1){
            int up = __shfl_up(ws, off, 16);
            if (t >= off) ws += up;
        }
        wsum[t] = ws;                  // inclusive wave totals
    }
    __syncthreads();
    int wbase = (wid == 0) ? 0 : wsum[wid-1];
    int run = wbase + sc - sum;        // exclusive prefix for this thread
    #pragma unroll
    for (int i=0;i<8;i++){ row_start[t*8+i] = run; cursor[t*8+i] = run; run += v[i]; }
    if (t == 1023) row_start[N_NODES] = wsum[15];
}

// ---- fused: CSR fill | alpha1 dots (grid-range split) -----------------------
// blocks [0,224): scatter edges into csr_src via cursor atomics
// blocks [224,1248): as1/ad1 dots, 8 nodes per block (256 thr, 2 half-groups)
__global__ __launch_bounds__(256) void k_fillalpha(const int* __restrict__ ei,
        int* cursor, int* __restrict__ csr_src,
        const float* __restrict__ x, const float* __restrict__ vv,
        float* __restrict__ as1, float* __restrict__ ad1){
    int b = blockIdx.x, t = threadIdx.x;
    if (b < 224){
        int i = b*256 + t;
        if (i >= E_TOT) return;
        int s, d;
        if (i < N_EDGES){ s = ei[i]; d = ei[N_EDGES + i]; }
        else { s = i - N_EDGES; d = s; }
        int pos = atomicAdd(&cursor[d], 1);
        csr_src[pos] = s;
    } else {
        __shared__ float xs[8][IN_F];   // 4 KB
        int bb = b - 224;               // 0..1023
        int nb = bb*8;
        {
            int r = t >> 5, c4 = t & 31;
            *(float4*)&xs[r][c4*4] = *(const float4*)(x + (size_t)(nb+r)*IN_F + c4*4);
        }
        __syncthreads();
        int half = t >> 7, tl = t & 127;
        int n0 = nb + half*4;
        float a0=0.f, a1=0.f, a2=0.f, a3=0.f;
        #pragma unroll 4
        for (int k=0;k<IN_F;k++){
            float v = vv[k*128 + tl];
            a0 += xs[half*4+0][k]*v; a1 += xs[half*4+1][k]*v;
            a2 += xs[half*4+2][k]*v; a3 += xs[half*4+3][k]*v;
        }
        int hd = tl & 63;
        float* outp = (tl < 64) ? as1 : ad1;
        outp[(n0+0)*NH1 + hd] = a0;
        outp[(n0+1)*NH1 + hd] = a1;
        outp[(n0+2)*NH1 + hd] = a2;
        outp[(n0+3)*NH1 + hd] = a3;
    }
}

// ------- x-space aggregation, ALL 64 heads, denom fused, single dispatch -----
__global__ __launch_bounds__(256) void k_aggx64(const float* __restrict__ x,
        const float* __restrict__ as1, const float* __restrict__ ad1,
        const int* __restrict__ row_start, const int* __restrict__ csr_src,
        unsigned short* __restrict__ txhi){
    int n = blockIdx.x, t = threadIdx.x;
    __shared__ float ad_s[NH1];
    __shared__ float wt[ET][NH1];   // 4 KB
    __shared__ int   st[ET];
    __shared__ float xs[ET][IN_F];  // 8 KB
    int e0 = row_start[n], e1 = row_start[n+1];
    if (t < NH1) ad_s[t] = ad1[n*NH1 + t];
    int hq = t >> 4, f0 = (t & 15)*8;
    float acc[4][8] = {};
    float D[4] = {0.f, 0.f, 0.f, 0.f};
    for (int eb = e0; eb < e1; eb += ET){
        int ne = min(ET, e1 - eb);
        if (t < ne) st[t] = csr_src[eb + t];
        __syncthreads();
        for (int idx = t; idx < ne*32; idx += 256){
            int e = idx >> 5, f4 = idx & 31;
            *(float4*)&xs[e][f4*4] = *(const float4*)(x + (size_t)st[e]*IN_F + f4*4);
        }
        for (int idx = t; idx < ne*NH1; idx += 256){
            int e = idx >> 6, hh = idx & 63;
            wt[e][hh] = __expf(lrelu(as1[st[e]*NH1 + hh] + ad_s[hh]));
        }
        __syncthreads();
        for (int e = 0; e < ne; e++){
            float4 v0 = *(const float4*)&xs[e][f0];
            float4 v1 = *(const float4*)&xs[e][f0+4];
            float xv[8] = {v0.x,v0.y,v0.z,v0.w,v1.x,v1.y,v1.z,v1.w};
            #pragma unroll
            for (int c=0;c<4;c++){
                float w = wt[e][hq*4 + c];
                D[c] += w;
                #pragma unroll
                for (int j=0;j<8;j++) acc[c][j] += w*xv[j];
            }
        }
        __syncthreads();
    }
    #pragma unroll
    for (int c=0;c<4;c++){
        float dinv = 1.f / D[c];
        bf16x8 hv;
        #pragma unroll
        for (int j=0;j<8;j++) hv[j] = (short)bf16_rne(acc[c][j] * dinv);
        size_t o = ((size_t)(hq*4 + c)*N_NODES + n)*IN_F + f0;
        *(bf16x8*)(txhi + o) = hv;
    }
}

// ------- FUSED layer-1 projection + ELU + layer-2 projection -----------------
// PROVEN R6/R11 kernel (~59.5 us): grid (128, NP=4) = 512 blocks; 80 KB LDS
// -> 2 blocks/CU. Wave tiling: wr in {0,1} 32-row tile (mi=2), wc in {0..3};
// GEMM2 col split {3,3,2,2}. W2 staged hi+lo in LDS once per iter; W1-lo in
// per-wave regs. Counted-vmcnt schedule (see R6 notes). NOTE: separate named
// __shared__ arrays are load-bearing (R13: flattening broke LDS alias analysis
// and cost 3.4x).
__global__ __launch_bounds__(512, 4) void k_gemm12(
        const unsigned short* __restrict__ txhi,
        const unsigned short* __restrict__ w1fh, const unsigned short* __restrict__ w1fl,
        const unsigned short* __restrict__ w2fh, const unsigned short* __restrict__ w2fl,
        const float* __restrict__ b1,
        float* __restrict__ P){
    __shared__ __attribute__((aligned(16))) unsigned short Als[8192];   // 16 KB A tile (64x128, XOR-swizzled)
    __shared__ __attribute__((aligned(16))) unsigned short W1sh[8192];  // 16 KB W1 hi-plane frags
    __shared__ __attribute__((aligned(16))) unsigned short W2s[20480];  // 40 KB W2 hi(0..10240)+lo frags
    __shared__ __attribute__((aligned(16))) unsigned short X1s[4096];   //  8 KB X1 tile (64x64, XOR-swizzled)

    const int tid  = threadIdx.x;
    const int wave = tid >> 6, lane = tid & 63;
    const int wr = wave & 1, wc = wave >> 1;
    const int q = lane >> 4, l16 = lane & 15;
    const int row0 = blockIdx.x * 64;
    const int g = blockIdx.y;
    const int h0 = g * HG;
    const int nbase = (wc < 2) ? wc*3 : 6 + (wc-2)*2;   // GEMM2 n-tile base

    // ---- prologue: stage A(h0) + W1hi(h0) (4 issues/wave) ----
    {
        const unsigned short* Ab = txhi + ((size_t)h0*N_NODES + row0)*IN_F;
        const unsigned short* W1b = w1fh + (size_t)h0*8192;
        #pragma unroll
        for (int j=0;j<2;j++){
            int idx = j*8 + wave;
            int eo = idx*512 + lane*8;
            int row = eo >> 7;
            int se = (eo & ~127) | ((eo & 127) ^ ((row & 7) << 3));
            gload_lds16(Ab + se, &Als[idx*512]);
        }
        #pragma unroll
        for (int j=0;j<2;j++){
            int idx = j*8 + wave;
            gload_lds16(W1b + idx*512 + lane*8, &W1sh[idx*512]);
        }
    }

    f32x4 acc2[2][3] = {};
    bf16x8 wlo[4];

    #pragma unroll 1
    for (int hh = 0; hh < HG; hh++){
        const int h = h0 + hh;
        block_sync_lds();                       // B_top: prev GEMM2 done with W2s/X1s
        // ---- W1 lo-plane fragments -> regs FIRST (oldest after staged A/W1hi) ----
        {
            const unsigned short* W1lb = w1fl + (size_t)h*8192;
            #pragma unroll
            for (int ks=0;ks<4;ks++)
                wlo[ks] = *(const bf16x8*)(W1lb + (size_t)(ks*4 + wc)*512 + lane*8);
        }
        asm volatile("" ::: "memory");          // pin: wlo issued before W2 staging
        // ---- stage W2 hi+lo for h (5 issues/wave) ----
        {
            const unsigned short* W2bh = w2fh + (size_t)h*10240;
            const unsigned short* W2bl = w2fl + (size_t)h*10240;
            #pragma unroll
            for (int j=0;j<5;j++){
                int idx = j*8 + wave;             // 0..39 (idx<20 -> hi plane)
                const unsigned short* src = (idx < 20) ? (W2bh + idx*512 + lane*8)
                                                       : (W2bl + (idx-20)*512 + lane*8);
                gload_lds16(src, &W2s[idx*512]);
            }
        }
        // outstanding: A/W1hi(4, oldest) + wlo(4) + W2(5) = 13 -> drain only A/W1hi
        asm volatile("s_waitcnt vmcnt(9)" ::: "memory");
        __builtin_amdgcn_s_barrier();           // B_mid: A/W1hi staging visible
        // ---- GEMM1: X1 = A[h] @ W1[h]^T (hi LDS, lo regs); B reused x2 ----
        f32x4 c1[2] = {};
        __builtin_amdgcn_s_setprio(1);
        #pragma unroll
        for (int ks=0;ks<4;ks++){
            bf16x8 bh = *(const bf16x8*)&W1sh[(ks*4 + wc)*512 + lane*8];
            #pragma unroll
            for (int mi=0;mi<2;mi++){
                int arow = wr*32 + mi*16 + l16;
                int sidx = (arow*128 + ks*32 + q*8) ^ ((arow & 7) << 3);
                bf16x8 af = *(const bf16x8*)&Als[sidx];
                c1[mi] = __builtin_amdgcn_mfma_f32_16x16x32_bf16(af, bh, c1[mi], 0,0,0);
                c1[mi] = __builtin_amdgcn_mfma_f32_16x16x32_bf16(af, wlo[ks], c1[mi], 0,0,0);
            }
        }
        __builtin_amdgcn_s_setprio(0);
        // ---- bias + fast ELU -> X1s (swizzled bf16) ----
        {
            int col = wc*16 + l16;
            float b = b1[h*64 + col];
            #pragma unroll
            for (int mi=0;mi<2;mi++){
                #pragma unroll
                for (int i=0;i<4;i++){
                    float v = c1[mi][i] + b;
                    float o = v > 0.f ? v : (__expf(v) - 1.f);
                    int row = wr*32 + mi*16 + q*4 + i;
                    int sidx = (row*64 + col) ^ ((row & 7) << 3);
                    X1s[sidx] = bf16_rne(o);
                }
            }
        }
        // drain W2 (only it remains in flight) under the GEMM1+ELU shadow
        asm volatile("s_waitcnt vmcnt(0) lgkmcnt(0)" ::: "memory");
        __builtin_amdgcn_s_barrier();           // B_vis: X1 + W2 staging visible
        // ---- stage A(h+1) + W1hi(h+1); loads fly across GEMM2 + next B_top ----
        if (hh + 1 < HG){
            const unsigned short* Ab = txhi + ((size_t)(h+1)*N_NODES + row0)*IN_F;
            const unsigned short* W1b = w1fh + (size_t)(h+1)*8192;
            #pragma unroll
            for (int j=0;j<2;j++){
                int idx = j*8 + wave;
                int eo = idx*512 + lane*8;
                int row = eo >> 7;
                int se = (eo & ~127) | ((eo & 127) ^ ((row & 7) << 3));
                gload_lds16(Ab + se, &Als[idx*512]);
            }
            #pragma unroll
            for (int j=0;j<2;j++){
                int idx = j*8 + wave;
                gload_lds16(W1b + idx*512 + lane*8, &W1sh[idx*512]);
            }
        }
        // ---- GEMM2: acc2 += X1 @ W2[h-slice]^T (all LDS); B reused x2 over mi ----
        __builtin_amdgcn_s_setprio(1);
        #pragma unroll
        for (int ks=0;ks<2;ks++){
            bf16x8 a2[2];
            #pragma unroll
            for (int mi=0;mi<2;mi++){
                int row = wr*32 + mi*16 + l16;
                int sidx = (row*64 + ks*32 + q*8) ^ ((row & 7) << 3);
                a2[mi] = *(const bf16x8*)&X1s[sidx];
            }
            if (wc < 2){
                #pragma unroll
                for (int ni=0;ni<3;ni++){
                    int f = (ks*10 + nbase + ni)*512 + lane*8;
                    bf16x8 bh = *(const bf16x8*)&W2s[f];
                    bf16x8 bl = *(const bf16x8*)&W2s[10240 + f];
                    #pragma unroll
                    for (int mi=0;mi<2;mi++){
                        acc2[mi][ni] = __builtin_amdgcn_mfma_f32_16x16x32_bf16(a2[mi], bh, acc2[mi][ni], 0,0,0);
                        acc2[mi][ni] = __builtin_amdgcn_mfma_f32_16x16x32_bf16(a2[mi], bl, acc2[mi][ni], 0,0,0);
                    }
                }
            } else {
                #pragma unroll
                for (int ni=0;ni<2;ni++){
                    int f = (ks*10 + nbase + ni)*512 + lane*8;
                    bf16x8 bh = *(const bf16x8*)&W2s[f];
                    bf16x8 bl = *(const bf16x8*)&W2s[10240 + f];
                    #pragma unroll
                    for (int mi=0;mi<2;mi++){
                        acc2[mi][ni] = __builtin_amdgcn_mfma_f32_16x16x32_bf16(a2[mi], bh, acc2[mi][ni], 0,0,0);
                        acc2[mi][ni] = __builtin_amdgcn_mfma_f32_16x16x32_bf16(a2[mi], bl, acc2[mi][ni], 0,0,0);
                    }
                }
            }
        }
        __builtin_amdgcn_s_setprio(0);
    }

    // ---- epilogue: head-group partial store ----
    float* outp = P + ((size_t)g*N_NODES + row0)*F2;
    #pragma unroll
    for (int mi=0;mi<2;mi++)
        #pragma unroll
        for (int ni=0;ni<3;ni++){
            if (wc >= 2 && ni >= 2) continue;    // wave-uniform; indices static
            #pragma unroll
            for (int i=0;i<4;i++){
                int rr = wr*32 + mi*16 + q*4 + i;
                int cc = (nbase + ni)*16 + l16;
                outp[(size_t)rr*F2 + cc] = acc2[mi][ni][i];
            }
        }
}

// ------- fused: reduce NP partials -> h2 AND layer-2 attention dots ----------
__global__ __launch_bounds__(256) void k_redalpha(const float* __restrict__ P,
        const float* __restrict__ att_s, const float* __restrict__ att_d,
        float* __restrict__ h2, float* __restrict__ as2, float* __restrict__ ad2){
    __shared__ float hs[32][164];   // 21 KB
    __shared__ float avs[160], avd[160];
    int b = blockIdx.x, t = threadIdx.x;
    int n0 = b*32;
    if (t < 160){ avs[t] = att_s[t]; avd[t] = att_d[t]; }
    const int NV = N_NODES*F2/4;
    int base = b * (32*F2/4);   // float4 index of this block's slab
    #pragma unroll
    for (int v=0; v<5; v++){
        int i = base + v*256 + t;
        float4 a = ((const float4*)P)[i];
        #pragma unroll
        for (int kb=1; kb<NP; kb++){
            float4 bb = ((const float4*)P)[(size_t)kb*NV + i];
            a.x+=bb.x; a.y+=bb.y; a.z+=bb.z; a.w+=bb.w;
        }
        ((float4*)h2)[i] = a;
        int flat = (v*256 + t)*4;          // 0..5116, never crosses a 160-row
        int n = flat / F2, c = flat % F2;
        *(float4*)&hs[n][c] = a;
    }
    __syncthreads();
    if (t < 160){
        int n = t/5, hh = t%5;
        const float* hp = &hs[n][hh*32];
        const float* ap = &avs[hh*32];
        const float* dp = &avd[hh*32];
        float s=0.f, d=0.f;
        #pragma unroll
        for (int c=0;c<32;c++){ float hv=hp[c]; s += hv*ap[c]; d += hv*dp[c]; }
        as2[(n0+n)*NH2 + hh] = s;
        ad2[(n0+n)*NH2 + hh] = d;
    }
}

// ------- layer-2 softmax + aggregation (SINGLE PASS) + head-mean + b2 --------
__global__ __launch_bounds__(192) void k_agg2(const float* __restrict__ h2,
        const float* __restrict__ as2, const float* __restrict__ ad2,
        const int* __restrict__ row_start, const int* __restrict__ csr_src,
        const float* __restrict__ b2, float* __restrict__ x2){
    int n = blockIdx.x, t = threadIdx.x;
    __shared__ float ad_s[NH2], sacc[F2];
    int e0 = row_start[n], e1 = row_start[n+1];
    if (t < NH2) ad_s[t] = ad2[n*NH2 + t];
    __syncthreads();
    if (t < F2){
        int h = t >> 5;
        float adh = ad_s[h];
        float acc = 0.f, D = 0.f;
        for (int e=e0;e<e1;e++){
            int s = csr_src[e];
            float w = __expf(lrelu(as2[s*NH2 + h] + adh));
            acc += w * h2[(size_t)s*F2 + t];
            D += w;
        }
        sacc[t] = acc / D;
    }
    __syncthreads();
    if (t < OUT_F){
        float v = (sacc[t] + sacc[t+32] + sacc[t+64] + sacc[t+96] + sacc[t+128]) * 0.2f + b2[t];
        x2[n*OUT_F + t] = v;
    }
}

// ---------------- bond scores + softmax over 64 bonds ----------------
__global__ __launch_bounds__(64) void k_bond(const float* __restrict__ x2,
        const int* __restrict__ lefts, const int* __restrict__ rights,
        float* __restrict__ out){
    int b = threadIdx.x;
    int L = lefts[b], R = rights[b];
    float s = 0.f;
    #pragma unroll
    for (int c=0;c<OUT_F;c+=4){
        float4 l4 = *(const float4*)(x2 + (size_t)L*OUT_F + c);
        float4 r4 = *(const float4*)(x2 + (size_t)R*OUT_F + c);
        s += l4.x+l4.y+l4.z+l4.w + r4.x+r4.y+r4.z+r4.w;
    }
    float m = s;
    #pragma unroll
    for (int off=1; off<64; off<<=1) m = fmaxf(m, __shfl_xor(m, off));
    float e = expf(s - m);
    float sum = e;
    #pragma unroll
    for (int off=1; off<64; off<<=1) sum += __shfl_xor(sum, off);
    out[b] = e / sum;
}

extern "C" void kernel_launch(void* const* d_in, const int* in_sizes, int n_in,
                              void* d_out, int out_size, void* d_ws, size_t ws_size,
                              hipStream_t stream){
    const float* x      = (const float*)d_in[0];
    const int*   ei     = (const int*)  d_in[1];
    const int*   lefts  = (const int*)  d_in[2];
    const int*   rights = (const int*)  d_in[3];
    const float* W1     = (const float*)d_in[4];
    const float* att_s1 = (const float*)d_in[5];
    const float* att_d1 = (const float*)d_in[6];
    const float* b1     = (const float*)d_in[7];
    const float* W2     = (const float*)d_in[8];
    const float* att_s2 = (const float*)d_in[9];
    const float* att_d2 = (const float*)d_in[10];
    const float* b2     = (const float*)d_in[11];
    float* out = (float*)d_out;

    // fixed layout (txhi 134 MB dominates)
    char* ws = (char*)d_ws;
    size_t off = 0;
    auto alloc = [&](size_t bytes) -> void* {
        void* p = ws + off;
        off += (bytes + 255) & ~(size_t)255;
        return p;
    };
    unsigned short* txhi = (unsigned short*)alloc((size_t)NH1*N_NODES*IN_F*2); // 134 MB
    float* part   = (float*)alloc((size_t)NP*N_NODES*F2*4);                    // 21 MB
    float* h2     = (float*)alloc((size_t)N_NODES*F2*4);
    float* as1    = (float*)alloc((size_t)N_NODES*NH1*4);
    float* ad1    = (float*)alloc((size_t)N_NODES*NH1*4);
    float* as2    = (float*)alloc((size_t)N_NODES*NH2*4);
    float* ad2    = (float*)alloc((size_t)N_NODES*NH2*4);
    float* x2     = (float*)alloc((size_t)N_NODES*OUT_F*4);
    float* vv     = (float*)alloc((size_t)IN_F*128*4);   // [k][128] s|d columns
    unsigned short* w1fh = (unsigned short*)alloc((size_t)F1*IN_F*2);
    unsigned short* w1fl = (unsigned short*)alloc((size_t)F1*IN_F*2);
    unsigned short* w2fh = (unsigned short*)alloc((size_t)128*10*512*2);
    unsigned short* w2fl = (unsigned short*)alloc((size_t)128*10*512*2);
    int* counts    = (int*)alloc((size_t)N_NODES*4);
    int* row_start = (int*)alloc((size_t)(N_NODES+1)*4);
    int* cursor    = (int*)alloc((size_t)N_NODES*4);
    int* csr_src   = (int*)alloc((size_t)E_TOT*4);

    // CSR count ∥ weight packs ∥ attention vectors (one dispatch)
    hipMemsetAsync(counts, 0, (size_t)N_NODES*4, stream);
    k_countprep<<<832, 256, 0, stream>>>(ei, counts, W1, W2, att_s1, att_d1,
                                         w1fh, w1fl, w2fh, w2fl, vv);
    k_scan<<<1, 1024, 0, stream>>>(counts, row_start, cursor);

    // CSR fill ∥ alpha1 dots (one dispatch; both deps satisfied after scan/prep)
    k_fillalpha<<<1248, 256, 0, stream>>>(ei, cursor, csr_src, x, vv, as1, ad1);

    // layer 1: single-pass aggregation (all heads)
    k_aggx64<<<N_NODES, 256, 0, stream>>>(x, as1, ad1, row_start, csr_src, txhi);

    // FUSED proj1 + ELU + proj2 (head-group partials) + fused reduce/alpha2
    k_gemm12<<<dim3(128, NP), 512, 0, stream>>>(txhi, w1fh, w1fl, w2fh, w2fl, b1, part);
    k_redalpha<<<256, 256, 0, stream>>>(part, att_s2, att_d2, h2, as2, ad2);

    // layer-2 aggregation: single-pass softmax (fused denominator)
    k_agg2<<<N_NODES, 192, 0, stream>>>(h2, as2, ad2, row_start, csr_src, b2, x2);

    k_bond<<<1, 64, 0, stream>>>(x2, lefts, rights, out);
}

// Round 16
// 208.888 us; speedup vs baseline: 1.7310x; 1.0032x over previous
//
#include <hip/hip_runtime.h>
#include <hip/hip_bf16.h>
#include <math.h>

#define N_NODES  8192
#define N_EDGES  49152
#define E_TOT    57344   // edges + self-loops
#define IN_F     128
#define HID      64
#define NH1      64
#define NH2      5
#define OUT_F    32
#define F1       4096    // NH1*HID
#define F2       160     // NH2*OUT_F
#define N_BONDS  64
#define ET       16      // aggx edge-tile
#define NP       4       // head-group partials for fused gemm12
#define HG       16      // heads per group = NH1/NP

typedef short bf16x8 __attribute__((ext_vector_type(8)));
typedef float f32x4  __attribute__((ext_vector_type(4)));

__device__ __forceinline__ float lrelu(float x){ return x > 0.f ? x : 0.2f*x; }

__device__ __forceinline__ unsigned short bf16_rne(float f){
    unsigned u = __float_as_uint(f);
    unsigned r = u + 0x7FFF + ((u >> 16) & 1);
    return (unsigned short)(r >> 16);
}
__device__ __forceinline__ float bf16f(unsigned short h){
    return __uint_as_float((unsigned)h << 16);
}

// barrier that drains LDS ops but leaves global loads (vmcnt) in flight
__device__ __forceinline__ void block_sync_lds(){
    asm volatile("s_waitcnt lgkmcnt(0)" ::: "memory");
    __builtin_amdgcn_s_barrier();
    asm volatile("" ::: "memory");
}

// async global->LDS, 16B per lane; LDS dest is the WAVE-UNIFORM chunk base
// (hardware writes base + lane*16). Global src is per-lane.
__device__ __forceinline__ void gload_lds16(const unsigned short* gp, unsigned short* lp_base){
    __builtin_amdgcn_global_load_lds(
        (const __attribute__((address_space(1))) unsigned int*)(const void*)gp,
        (__attribute__((address_space(3))) unsigned int*)(void*)lp_base,
        16, 0, 0);
}

// ---- fused: edge-count | W1 pack | W2 pack | attention vectors --------------
// blocks [0,192): count in-degrees (atomics into zeroed counts)
// blocks [192,448): W1 -> split-bf16 frag order [hg][ks][ct][lane][8]
// blocks [448,768): W2 -> split-bf16 frag order [kc][ni][lane][8]
// blocks [768,832): vv column-major [k][j]
__global__ __launch_bounds__(256) void k_countprep(const int* __restrict__ ei,
        int* counts,
        const float* __restrict__ W1, const float* __restrict__ W2,
        const float* __restrict__ a_s, const float* __restrict__ a_d,
        unsigned short* __restrict__ w1fh, unsigned short* __restrict__ w1fl,
        unsigned short* __restrict__ w2fh, unsigned short* __restrict__ w2fl,
        float* __restrict__ vv){
    int b = blockIdx.x, t = threadIdx.x;
    if (b < 192){
        int i = b*256 + t;
        if (i < N_EDGES) atomicAdd(&counts[ei[N_EDGES + i]], 1);
    } else if (b < 448){
        int g = (b-192)*256 + t;                  // 65536 groups
        int lane = g & 63, ct = (g >> 6) & 3, ks = (g >> 8) & 3, hg = g >> 10;
        int col = hg*64 + ct*16 + (lane & 15);
        int k = ks*32 + (lane >> 4)*8;
        const float* src = W1 + (size_t)col*IN_F + k;
        bf16x8 hv, lv;
        #pragma unroll
        for (int j=0;j<8;j++){
            float f = src[j];
            unsigned short hb = bf16_rne(f);
            hv[j] = (short)hb;
            lv[j] = (short)bf16_rne(f - bf16f(hb));
        }
        *(bf16x8*)(w1fh + (size_t)g*8) = hv;
        *(bf16x8*)(w1fl + (size_t)g*8) = lv;
    } else if (b < 768){
        int g = (b-448)*256 + t;                  // 81920 groups
        int lane = g & 63, ni = (g >> 6) % 10, kc = g / 640;
        int n = ni*16 + (lane & 15);
        int k = kc*32 + (lane >> 4)*8;
        const float* src = W2 + (size_t)n*F1 + k;
        bf16x8 hv, lv;
        #pragma unroll
        for (int j=0;j<8;j++){
            float f = src[j];
            unsigned short hb = bf16_rne(f);
            hv[j] = (short)hb;
            lv[j] = (short)bf16_rne(f - bf16f(hb));
        }
        *(bf16x8*)(w2fh + (size_t)g*8) = hv;
        *(bf16x8*)(w2fl + (size_t)g*8) = lv;
    } else {
        int idx = (b-768)*256 + t;                // 16384 = 128 j x 128 k
        int j = idx >> 7, k = idx & 127;
        int h = j & 63;
        const float* ap = (j < 64) ? a_s : a_d;
        float s = 0.f;
        for (int c = 0; c < HID; c++)
            s += ap[h*HID + c] * W1[(size_t)(h*HID + c)*IN_F + k];
        vv[k*128 + j] = s;
    }
}

// counts hold in-degree WITHOUT self-loop (zeroed via memset); scan adds +1.
// Wave-level shfl scan: 2 barriers (bit-exact integer adds).
__global__ __launch_bounds__(1024) void k_scan(const int* __restrict__ counts,
                                               int* __restrict__ row_start,
                                               int* __restrict__ cursor){
    __shared__ int wsum[16];
    int t = threadIdx.x;
    int v[8]; int sum = 0;
    #pragma unroll
    for (int i=0;i<8;i++){ v[i] = counts[t*8+i] + 1; sum += v[i]; }
    int sc = sum;
    #pragma unroll
    for (int off=1; off<64; off<<=1){
        int up = __shfl_up(sc, off);
        if ((t & 63) >= off) sc += up;
    }
    int wid = t >> 6;
    if ((t & 63) == 63) wsum[wid] = sc;
    __syncthreads();
    if (t < 16){
        int ws = wsum[t];
        #pragma unroll
        for (int off=1; off<16; off<<=1){
            int up = __shfl_up(ws, off, 16);
            if (t >= off) ws += up;
        }
        wsum[t] = ws;                  // inclusive wave totals
    }
    __syncthreads();
    int wbase = (wid == 0) ? 0 : wsum[wid-1];
    int run = wbase + sc - sum;        // exclusive prefix for this thread
    #pragma unroll
    for (int i=0;i<8;i++){ row_start[t*8+i] = run; cursor[t*8+i] = run; run += v[i]; }
    if (t == 1023) row_start[N_NODES] = wsum[15];
}

// ---- fused: CSR fill | alpha1 dots (grid-range split) -----------------------
// blocks [0,224): scatter edges into csr_src via cursor atomics
// blocks [224,1248): as1/ad1 dots, 8 nodes per block (256 thr, 2 half-groups)
__global__ __launch_bounds__(256) void k_fillalpha(const int* __restrict__ ei,
        int* cursor, int* __restrict__ csr_src,
        const float* __restrict__ x, const float* __restrict__ vv,
        float* __restrict__ as1, float* __restrict__ ad1){
    int b = blockIdx.x, t = threadIdx.x;
    if (b < 224){
        int i = b*256 + t;
        if (i >= E_TOT) return;
        int s, d;
        if (i < N_EDGES){ s = ei[i]; d = ei[N_EDGES + i]; }
        else { s = i - N_EDGES; d = s; }
        int pos = atomicAdd(&cursor[d], 1);
        csr_src[pos] = s;
    } else {
        __shared__ float xs[8][IN_F];   // 4 KB
        int bb = b - 224;               // 0..1023
        int nb = bb*8;
        {
            int r = t >> 5, c4 = t & 31;
            *(float4*)&xs[r][c4*4] = *(const float4*)(x + (size_t)(nb+r)*IN_F + c4*4);
        }
        __syncthreads();
        int half = t >> 7, tl = t & 127;
        int n0 = nb + half*4;
        float a0=0.f, a1=0.f, a2=0.f, a3=0.f;
        #pragma unroll 4
        for (int k=0;k<IN_F;k++){
            float v = vv[k*128 + tl];
            a0 += xs[half*4+0][k]*v; a1 += xs[half*4+1][k]*v;
            a2 += xs[half*4+2][k]*v; a3 += xs[half*4+3][k]*v;
        }
        int hd = tl & 63;
        float* outp = (tl < 64) ? as1 : ad1;
        outp[(n0+0)*NH1 + hd] = a0;
        outp[(n0+1)*NH1 + hd] = a1;
        outp[(n0+2)*NH1 + hd] = a2;
        outp[(n0+3)*NH1 + hd] = a3;
    }
}

// ------- x-space aggregation, ALL 64 heads, denom fused, single dispatch -----
__global__ __launch_bounds__(256) void k_aggx64(const float* __restrict__ x,
        const float* __restrict__ as1, const float* __restrict__ ad1,
        const int* __restrict__ row_start, const int* __restrict__ csr_src,
        unsigned short* __restrict__ txhi){
    int n = blockIdx.x, t = threadIdx.x;
    __shared__ float ad_s[NH1];
    __shared__ float wt[ET][NH1];   // 4 KB
    __shared__ int   st[ET];
    __shared__ float xs[ET][IN_F];  // 8 KB
    int e0 = row_start[n], e1 = row_start[n+1];
    if (t < NH1) ad_s[t] = ad1[n*NH1 + t];
    int hq = t >> 4, f0 = (t & 15)*8;
    float acc[4][8] = {};
    float D[4] = {0.f, 0.f, 0.f, 0.f};
    for (int eb = e0; eb < e1; eb += ET){
        int ne = min(ET, e1 - eb);
        if (t < ne) st[t] = csr_src[eb + t];
        __syncthreads();
        for (int idx = t; idx < ne*32; idx += 256){
            int e = idx >> 5, f4 = idx & 31;
            *(float4*)&xs[e][f4*4] = *(const float4*)(x + (size_t)st[e]*IN_F + f4*4);
        }
        for (int idx = t; idx < ne*NH1; idx += 256){
            int e = idx >> 6, hh = idx & 63;
            wt[e][hh] = __expf(lrelu(as1[st[e]*NH1 + hh] + ad_s[hh]));
        }
        __syncthreads();
        for (int e = 0; e < ne; e++){
            float4 v0 = *(const float4*)&xs[e][f0];
            float4 v1 = *(const float4*)&xs[e][f0+4];
            float xv[8] = {v0.x,v0.y,v0.z,v0.w,v1.x,v1.y,v1.z,v1.w};
            #pragma unroll
            for (int c=0;c<4;c++){
                float w = wt[e][hq*4 + c];
                D[c] += w;
                #pragma unroll
                for (int j=0;j<8;j++) acc[c][j] += w*xv[j];
            }
        }
        __syncthreads();
    }
    #pragma unroll
    for (int c=0;c<4;c++){
        float dinv = 1.f / D[c];
        bf16x8 hv;
        #pragma unroll
        for (int j=0;j<8;j++) hv[j] = (short)bf16_rne(acc[c][j] * dinv);
        size_t o = ((size_t)(hq*4 + c)*N_NODES + n)*IN_F + f0;
        *(bf16x8*)(txhi + o) = hv;
    }
}

// ------- FUSED layer-1 projection + ELU + layer-2 projection -----------------
// PROVEN R6/R11 kernel (~59.5 us) + XCD-aware block swizzle (R16): flat 512-
// block grid; g = (flat%8)>>1, rb = ((flat%8)&1)*64 + flat/8. Each head-group's
// 128 row-blocks concentrate on 2 XCDs -> shared weight frags fetched into 2
// L2s instead of 8 (txhi unaffected: each byte read by exactly one block).
// 80 KB LDS -> 2 blocks/CU. Wave tiling: wr in {0,1} 32-row tile (mi=2), wc in
// {0..3}; GEMM2 col split {3,3,2,2}. W2 staged hi+lo in LDS once per iter;
// W1-lo in per-wave regs. Counted-vmcnt schedule (see R6 notes). NOTE: separate
// named __shared__ arrays are load-bearing (R13: flattening broke LDS alias
// analysis, 3.4x regression).
__global__ __launch_bounds__(512, 4) void k_gemm12(
        const unsigned short* __restrict__ txhi,
        const unsigned short* __restrict__ w1fh, const unsigned short* __restrict__ w1fl,
        const unsigned short* __restrict__ w2fh, const unsigned short* __restrict__ w2fl,
        const float* __restrict__ b1,
        float* __restrict__ P){
    __shared__ __attribute__((aligned(16))) unsigned short Als[8192];   // 16 KB A tile (64x128, XOR-swizzled)
    __shared__ __attribute__((aligned(16))) unsigned short W1sh[8192];  // 16 KB W1 hi-plane frags
    __shared__ __attribute__((aligned(16))) unsigned short W2s[20480];  // 40 KB W2 hi(0..10240)+lo frags
    __shared__ __attribute__((aligned(16))) unsigned short X1s[4096];   //  8 KB X1 tile (64x64, XOR-swizzled)

    const int tid  = threadIdx.x;
    const int wave = tid >> 6, lane = tid & 63;
    const int wr = wave & 1, wc = wave >> 1;
    const int q = lane >> 4, l16 = lane & 15;
    // XCD swizzle: concentrate each head-group on 2 XCDs (bijective remap)
    const int flat = blockIdx.x;
    const int xcd  = flat & 7, slot = flat >> 3;
    const int g    = xcd >> 1;
    const int row0 = ((xcd & 1)*64 + slot) * 64;
    const int h0 = g * HG;
    const int nbase = (wc < 2) ? wc*3 : 6 + (wc-2)*2;   // GEMM2 n-tile base

    // ---- prologue: stage A(h0) + W1hi(h0) (4 issues/wave) ----
    {
        const unsigned short* Ab = txhi + ((size_t)h0*N_NODES + row0)*IN_F;
        const unsigned short* W1b = w1fh + (size_t)h0*8192;
        #pragma unroll
        for (int j=0;j<2;j++){
            int idx = j*8 + wave;
            int eo = idx*512 + lane*8;
            int row = eo >> 7;
            int se = (eo & ~127) | ((eo & 127) ^ ((row & 7) << 3));
            gload_lds16(Ab + se, &Als[idx*512]);
        }
        #pragma unroll
        for (int j=0;j<2;j++){
            int idx = j*8 + wave;
            gload_lds16(W1b + idx*512 + lane*8, &W1sh[idx*512]);
        }
    }

    f32x4 acc2[2][3] = {};
    bf16x8 wlo[4];

    #pragma unroll 1
    for (int hh = 0; hh < HG; hh++){
        const int h = h0 + hh;
        block_sync_lds();                       // B_top: prev GEMM2 done with W2s/X1s
        // ---- W1 lo-plane fragments -> regs FIRST (oldest after staged A/W1hi) ----
        {
            const unsigned short* W1lb = w1fl + (size_t)h*8192;
            #pragma unroll
            for (int ks=0;ks<4;ks++)
                wlo[ks] = *(const bf16x8*)(W1lb + (size_t)(ks*4 + wc)*512 + lane*8);
        }
        asm volatile("" ::: "memory");          // pin: wlo issued before W2 staging
        // ---- stage W2 hi+lo for h (5 issues/wave) ----
        {
            const unsigned short* W2bh = w2fh + (size_t)h*10240;
            const unsigned short* W2bl = w2fl + (size_t)h*10240;
            #pragma unroll
            for (int j=0;j<5;j++){
                int idx = j*8 + wave;             // 0..39 (idx<20 -> hi plane)
                const unsigned short* src = (idx < 20) ? (W2bh + idx*512 + lane*8)
                                                       : (W2bl + (idx-20)*512 + lane*8);
                gload_lds16(src, &W2s[idx*512]);
            }
        }
        // outstanding: A/W1hi(4, oldest) + wlo(4) + W2(5) = 13 -> drain only A/W1hi
        asm volatile("s_waitcnt vmcnt(9)" ::: "memory");
        __builtin_amdgcn_s_barrier();           // B_mid: A/W1hi staging visible
        // ---- GEMM1: X1 = A[h] @ W1[h]^T (hi LDS, lo regs); B reused x2 ----
        f32x4 c1[2] = {};
        __builtin_amdgcn_s_setprio(1);
        #pragma unroll
        for (int ks=0;ks<4;ks++){
            bf16x8 bh = *(const bf16x8*)&W1sh[(ks*4 + wc)*512 + lane*8];
            #pragma unroll
            for (int mi=0;mi<2;mi++){
                int arow = wr*32 + mi*16 + l16;
                int sidx = (arow*128 + ks*32 + q*8) ^ ((arow & 7) << 3);
                bf16x8 af = *(const bf16x8*)&Als[sidx];
                c1[mi] = __builtin_amdgcn_mfma_f32_16x16x32_bf16(af, bh, c1[mi], 0,0,0);
                c1[mi] = __builtin_amdgcn_mfma_f32_16x16x32_bf16(af, wlo[ks], c1[mi], 0,0,0);
            }
        }
        __builtin_amdgcn_s_setprio(0);
        // ---- bias + fast ELU -> X1s (swizzled bf16) ----
        {
            int col = wc*16 + l16;
            float b = b1[h*64 + col];
            #pragma unroll
            for (int mi=0;mi<2;mi++){
                #pragma unroll
                for (int i=0;i<4;i++){
                    float v = c1[mi][i] + b;
                    float o = v > 0.f ? v : (__expf(v) - 1.f);
                    int row = wr*32 + mi*16 + q*4 + i;
                    int sidx = (row*64 + col) ^ ((row & 7) << 3);
                    X1s[sidx] = bf16_rne(o);
                }
            }
        }
        // drain W2 (only it remains in flight) under the GEMM1+ELU shadow
        asm volatile("s_waitcnt vmcnt(0) lgkmcnt(0)" ::: "memory");
        __builtin_amdgcn_s_barrier();           // B_vis: X1 + W2 staging visible
        // ---- stage A(h+1) + W1hi(h+1); loads fly across GEMM2 + next B_top ----
        if (hh + 1 < HG){
            const unsigned short* Ab = txhi + ((size_t)(h+1)*N_NODES + row0)*IN_F;
            const unsigned short* W1b = w1fh + (size_t)(h+1)*8192;
            #pragma unroll
            for (int j=0;j<2;j++){
                int idx = j*8 + wave;
                int eo = idx*512 + lane*8;
                int row = eo >> 7;
                int se = (eo & ~127) | ((eo & 127) ^ ((row & 7) << 3));
                gload_lds16(Ab + se, &Als[idx*512]);
            }
            #pragma unroll
            for (int j=0;j<2;j++){
                int idx = j*8 + wave;
                gload_lds16(W1b + idx*512 + lane*8, &W1sh[idx*512]);
            }
        }
        // ---- GEMM2: acc2 += X1 @ W2[h-slice]^T (all LDS); B reused x2 over mi ----
        __builtin_amdgcn_s_setprio(1);
        #pragma unroll
        for (int ks=0;ks<2;ks++){
            bf16x8 a2[2];
            #pragma unroll
            for (int mi=0;mi<2;mi++){
                int row = wr*32 + mi*16 + l16;
                int sidx = (row*64 + ks*32 + q*8) ^ ((row & 7) << 3);
                a2[mi] = *(const bf16x8*)&X1s[sidx];
            }
            if (wc < 2){
                #pragma unroll
                for (int ni=0;ni<3;ni++){
                    int f = (ks*10 + nbase + ni)*512 + lane*8;
                    bf16x8 bh = *(const bf16x8*)&W2s[f];
                    bf16x8 bl = *(const bf16x8*)&W2s[10240 + f];
                    #pragma unroll
                    for (int mi=0;mi<2;mi++){
                        acc2[mi][ni] = __builtin_amdgcn_mfma_f32_16x16x32_bf16(a2[mi], bh, acc2[mi][ni], 0,0,0);
                        acc2[mi][ni] = __builtin_amdgcn_mfma_f32_16x16x32_bf16(a2[mi], bl, acc2[mi][ni], 0,0,0);
                    }
                }
            } else {
                #pragma unroll
                for (int ni=0;ni<2;ni++){
                    int f = (ks*10 + nbase + ni)*512 + lane*8;
                    bf16x8 bh = *(const bf16x8*)&W2s[f];
                    bf16x8 bl = *(const bf16x8*)&W2s[10240 + f];
                    #pragma unroll
                    for (int mi=0;mi<2;mi++){
                        acc2[mi][ni] = __builtin_amdgcn_mfma_f32_16x16x32_bf16(a2[mi], bh, acc2[mi][ni], 0,0,0);
                        acc2[mi][ni] = __builtin_amdgcn_mfma_f32_16x16x32_bf16(a2[mi], bl, acc2[mi][ni], 0,0,0);
                    }
                }
            }
        }
        __builtin_amdgcn_s_setprio(0);
    }

    // ---- epilogue: head-group partial store ----
    float* outp = P + ((size_t)g*N_NODES + row0)*F2;
    #pragma unroll
    for (int mi=0;mi<2;mi++)
        #pragma unroll
        for (int ni=0;ni<3;ni++){
            if (wc >= 2 && ni >= 2) continue;    // wave-uniform; indices static
            #pragma unroll
            for (int i=0;i<4;i++){
                int rr = wr*32 + mi*16 + q*4 + i;
                int cc = (nbase + ni)*16 + l16;
                outp[(size_t)rr*F2 + cc] = acc2[mi][ni][i];
            }
        }
}

// ------- fused: reduce NP partials -> h2 AND layer-2 attention dots ----------
__global__ __launch_bounds__(256) void k_redalpha(const float* __restrict__ P,
        const float* __restrict__ att_s, const float* __restrict__ att_d,
        float* __restrict__ h2, float* __restrict__ as2, float* __restrict__ ad2){
    __shared__ float hs[32][164];   // 21 KB
    __shared__ float avs[160], avd[160];
    int b = blockIdx.x, t = threadIdx.x;
    int n0 = b*32;
    if (t < 160){ avs[t] = att_s[t]; avd[t] = att_d[t]; }
    const int NV = N_NODES*F2/4;
    int base = b * (32*F2/4);   // float4 index of this block's slab
    #pragma unroll
    for (int v=0; v<5; v++){
        int i = base + v*256 + t;
        float4 a = ((const float4*)P)[i];
        #pragma unroll
        for (int kb=1; kb<NP; kb++){
            float4 bb = ((const float4*)P)[(size_t)kb*NV + i];
            a.x+=bb.x; a.y+=bb.y; a.z+=bb.z; a.w+=bb.w;
        }
        ((float4*)h2)[i] = a;
        int flat = (v*256 + t)*4;          // 0..5116, never crosses a 160-row
        int n = flat / F2, c = flat % F2;
        *(float4*)&hs[n][c] = a;
    }
    __syncthreads();
    if (t < 160){
        int n = t/5, hh = t%5;
        const float* hp = &hs[n][hh*32];
        const float* ap = &avs[hh*32];
        const float* dp = &avd[hh*32];
        float s=0.f, d=0.f;
        #pragma unroll
        for (int c=0;c<32;c++){ float hv=hp[c]; s += hv*ap[c]; d += hv*dp[c]; }
        as2[(n0+n)*NH2 + hh] = s;
        ad2[(n0+n)*NH2 + hh] = d;
    }
}

// ------- layer-2 softmax + aggregation (SINGLE PASS) + head-mean + b2 --------
__global__ __launch_bounds__(192) void k_agg2(const float* __restrict__ h2,
        const float* __restrict__ as2, const float* __restrict__ ad2,
        const int* __restrict__ row_start, const int* __restrict__ csr_src,
        const float* __restrict__ b2, float* __restrict__ x2){
    int n = blockIdx.x, t = threadIdx.x;
    __shared__ float ad_s[NH2], sacc[F2];
    int e0 = row_start[n], e1 = row_start[n+1];
    if (t < NH2) ad_s[t] = ad2[n*NH2 + t];
    __syncthreads();
    if (t < F2){
        int h = t >> 5;
        float adh = ad_s[h];
        float acc = 0.f, D = 0.f;
        for (int e=e0;e<e1;e++){
            int s = csr_src[e];
            float w = __expf(lrelu(as2[s*NH2 + h] + adh));
            acc += w * h2[(size_t)s*F2 + t];
            D += w;
        }
        sacc[t] = acc / D;
    }
    __syncthreads();
    if (t < OUT_F){
        float v = (sacc[t] + sacc[t+32] + sacc[t+64] + sacc[t+96] + sacc[t+128]) * 0.2f + b2[t];
        x2[n*OUT_F + t] = v;
    }
}

// ---------------- bond scores + softmax over 64 bonds ----------------
__global__ __launch_bounds__(64) void k_bond(const float* __restrict__ x2,
        const int* __restrict__ lefts, const int* __restrict__ rights,
        float* __restrict__ out){
    int b = threadIdx.x;
    int L = lefts[b], R = rights[b];
    float s = 0.f;
    #pragma unroll
    for (int c=0;c<OUT_F;c+=4){
        float4 l4 = *(const float4*)(x2 + (size_t)L*OUT_F + c);
        float4 r4 = *(const float4*)(x2 + (size_t)R*OUT_F + c);
        s += l4.x+l4.y+l4.z+l4.w + r4.x+r4.y+r4.z+r4.w;
    }
    float m = s;
    #pragma unroll
    for (int off=1; off<64; off<<=1) m = fmaxf(m, __shfl_xor(m, off));
    float e = expf(s - m);
    float sum = e;
    #pragma unroll
    for (int off=1; off<64; off<<=1) sum += __shfl_xor(sum, off);
    out[b] = e / sum;
}

extern "C" void kernel_launch(void* const* d_in, const int* in_sizes, int n_in,
                              void* d_out, int out_size, void* d_ws, size_t ws_size,
                              hipStream_t stream){
    const float* x      = (const float*)d_in[0];
    const int*   ei     = (const int*)  d_in[1];
    const int*   lefts  = (const int*)  d_in[2];
    const int*   rights = (const int*)  d_in[3];
    const float* W1     = (const float*)d_in[4];
    const float* att_s1 = (const float*)d_in[5];
    const float* att_d1 = (const float*)d_in[6];
    const float* b1     = (const float*)d_in[7];
    const float* W2     = (const float*)d_in[8];
    const float* att_s2 = (const float*)d_in[9];
    const float* att_d2 = (const float*)d_in[10];
    const float* b2     = (const float*)d_in[11];
    float* out = (float*)d_out;

    // fixed layout (txhi 134 MB dominates)
    char* ws = (char*)d_ws;
    size_t off = 0;
    auto alloc = [&](size_t bytes) -> void* {
        void* p = ws + off;
        off += (bytes + 255) & ~(size_t)255;
        return p;
    };
    unsigned short* txhi = (unsigned short*)alloc((size_t)NH1*N_NODES*IN_F*2); // 134 MB
    float* part   = (float*)alloc((size_t)NP*N_NODES*F2*4);                    // 21 MB
    float* h2     = (float*)alloc((size_t)N_NODES*F2*4);
    float* as1    = (float*)alloc((size_t)N_NODES*NH1*4);
    float* ad1    = (float*)alloc((size_t)N_NODES*NH1*4);
    float* as2    = (float*)alloc((size_t)N_NODES*NH2*4);
    float* ad2    = (float*)alloc((size_t)N_NODES*NH2*4);
    float* x2     = (float*)alloc((size_t)N_NODES*OUT_F*4);
    float* vv     = (float*)alloc((size_t)IN_F*128*4);   // [k][128] s|d columns
    unsigned short* w1fh = (unsigned short*)alloc((size_t)F1*IN_F*2);
    unsigned short* w1fl = (unsigned short*)alloc((size_t)F1*IN_F*2);
    unsigned short* w2fh = (unsigned short*)alloc((size_t)128*10*512*2);
    unsigned short* w2fl = (unsigned short*)alloc((size_t)128*10*512*2);
    int* counts    = (int*)alloc((size_t)N_NODES*4);
    int* row_start = (int*)alloc((size_t)(N_NODES+1)*4);
    int* cursor    = (int*)alloc((size_t)N_NODES*4);
    int* csr_src   = (int*)alloc((size_t)E_TOT*4);

    // CSR count ∥ weight packs ∥ attention vectors (one dispatch)
    hipMemsetAsync(counts, 0, (size_t)N_NODES*4, stream);
    k_countprep<<<832, 256, 0, stream>>>(ei, counts, W1, W2, att_s1, att_d1,
                                         w1fh, w1fl, w2fh, w2fl, vv);
    k_scan<<<1, 1024, 0, stream>>>(counts, row_start, cursor);

    // CSR fill ∥ alpha1 dots (one dispatch; both deps satisfied after scan/prep)
    k_fillalpha<<<1248, 256, 0, stream>>>(ei, cursor, csr_src, x, vv, as1, ad1);

    // layer 1: single-pass aggregation (all heads)
    k_aggx64<<<N_NODES, 256, 0, stream>>>(x, as1, ad1, row_start, csr_src, txhi);

    // FUSED proj1 + ELU + proj2 (XCD-swizzled flat grid) + fused reduce/alpha2
    k_gemm12<<<512, 512, 0, stream>>>(txhi, w1fh, w1fl, w2fh, w2fl, b1, part);
    k_redalpha<<<256, 256, 0, stream>>>(part, att_s2, att_d2, h2, as2, ad2);

    // layer-2 aggregation: single-pass softmax (fused denominator)
    k_agg2<<<N_NODES, 192, 0, stream>>>(h2, as2, ad2, row_start, csr_src, b2, x2);

    k_bond<<<1, 64, 0, stream>>>(x2, lefts, rights, out);
}